// Round 12
// baseline (57.114 us; speedup 1.0000x reference)
//
#include <hip/hip_runtime.h>
#include <string.h>

#define AA (-0.75f)

__device__ __forceinline__ float k1f(float x) {
    return ((AA + 2.0f) * x - (AA + 3.0f)) * x * x + 1.0f;
}
__device__ __forceinline__ float k2f(float x) {
    return ((AA * x - 5.0f * AA) * x + 8.0f * AA) * x - 4.0f * AA;
}

__device__ __forceinline__ int reflect_clip(int idx, int size) {
    int span = size - 1;
    int i = idx < 0 ? -idx : idx;
    i = i % (2 * span);
    if (i > span) i = 2 * span - i;
    return i;
}

// LDS bank swizzle: logical element a -> a ^ ((a>>5)&31). Bijective per row.
__device__ __forceinline__ int swz(int a) { return a ^ ((a >> 5) & 31); }

typedef float f32x2 __attribute__((ext_vector_type(2)));
typedef float f32x4 __attribute__((ext_vector_type(4)));

// One instruction, two dword reads 8192B apart (32 x 256B): channels c, c+4.
#define DSR2(dst, a)                                                        \
    asm volatile("ds_read2st64_b32 %0, %1 offset0:0 offset1:32"             \
                 : "=v"(dst) : "v"(a))

// Separable bicubic, one block per (b,h), 256 threads. R5 structure; phase 2
// LDS reads halved via ds_read2st64_b32 (64 -> 32 insts/thread), pipelined
// 2 groups deep with counted lgkmcnt + sched_barrier (rule #18).
__global__ __launch_bounds__(256, 4)
void pds12_kernel(const float* __restrict__ x,
                  const float* __restrict__ rate,
                  const float* __restrict__ center,
                  float* __restrict__ out)
{
    constexpr int C = 8, H = 512, W = 512, HW = H * W;

    // XCD-chunked remap (8192 % 8 == 0 -> bijective).
    const int orig = blockIdx.x;
    const int id = (orig & 7) * 1024 + (orig >> 3);
    const int b = id >> 9;
    const int h = id & (H - 1);

    const float r  = rate[b];
    const float cx = center[2 * b + 0];
    const float cy = center[2 * b + 1];
    const float inv_r = 1.0f / r;
    const int t = threadIdx.x;

    // ---- y taps (block-uniform, short chain) ----
    const float gy = 0.00390625f * (float)h - 1.0f;
    const float Gy = (gy - cy) * inv_r + cy;
    const float iy = (Gy + 1.0f) * 0.5f * 511.0f;
    const float y0 = floorf(iy);
    const float ty = iy - y0;
    const int   y0i = (int)y0;
    const float wy0 = k2f(ty + 1.0f);
    const float wy1 = k1f(ty);
    const float wy2 = k1f(1.0f - ty);
    const float wy3 = k2f(2.0f - ty);
    const int ro0 = reflect_clip(y0i - 1, H) * W;
    const int ro1 = reflect_clip(y0i    , H) * W;
    const int ro2 = reflect_clip(y0i + 1, H) * W;
    const int ro3 = reflect_clip(y0i + 2, H) * W;

    // ---- phase-1: 16 float4 loads (compiler-scheduled, R5-proven) ----
    const float* imgb = x + (size_t)b * C * HW;
    const int cc4 = (t & 127) << 2;           // 16B-aligned group in row
    const int ch0 = (t >> 7);                 // 0 or 1
    const float* base0 = imgb + (size_t)(ch0 + 0) * HW + cc4;
    const float* base1 = imgb + (size_t)(ch0 + 2) * HW + cc4;
    const float* base2 = imgb + (size_t)(ch0 + 4) * HW + cc4;
    const float* base3 = imgb + (size_t)(ch0 + 6) * HW + cc4;

    f32x4 p00 = *(const f32x4*)(base0 + ro0);
    f32x4 p01 = *(const f32x4*)(base0 + ro1);
    f32x4 p02 = *(const f32x4*)(base0 + ro2);
    f32x4 p03 = *(const f32x4*)(base0 + ro3);
    f32x4 p10 = *(const f32x4*)(base1 + ro0);
    f32x4 p11 = *(const f32x4*)(base1 + ro1);
    f32x4 p12 = *(const f32x4*)(base1 + ro2);
    f32x4 p13 = *(const f32x4*)(base1 + ro3);
    f32x4 p20 = *(const f32x4*)(base2 + ro0);
    f32x4 p21 = *(const f32x4*)(base2 + ro1);
    f32x4 p22 = *(const f32x4*)(base2 + ro2);
    f32x4 p23 = *(const f32x4*)(base2 + ro3);
    f32x4 p30 = *(const f32x4*)(base3 + ro0);
    f32x4 p31 = *(const f32x4*)(base3 + ro1);
    f32x4 p32 = *(const f32x4*)(base3 + ro2);
    f32x4 p33 = *(const f32x4*)(base3 + ro3);
    asm volatile("" ::: "memory");

    // ---- x taps for cols 2t, 2t+1 (VALU under load flight) ----
    int   sA0, sA1, sA2, sA3, sB0, sB1, sB2, sB3;
    float wxA0, wxA1, wxA2, wxA3, wxB0, wxB1, wxB2, wxB3;
    {
        const int w = 2 * t;
        const float gx = 0.00390625f * (float)w - 1.0f;
        const float Gx = (gx - cx) * inv_r + cx;
        const float ix = (Gx + 1.0f) * 0.5f * 511.0f;
        const float x0 = floorf(ix);
        const float tx = ix - x0;
        const int x0i = (int)x0;
        wxA0 = k2f(tx + 1.0f); wxA1 = k1f(tx);
        wxA2 = k1f(1.0f - tx); wxA3 = k2f(2.0f - tx);
        sA0 = swz(reflect_clip(x0i - 1, W)); sA1 = swz(reflect_clip(x0i,     W));
        sA2 = swz(reflect_clip(x0i + 1, W)); sA3 = swz(reflect_clip(x0i + 2, W));
    }
    {
        const int w = 2 * t + 1;
        const float gx = 0.00390625f * (float)w - 1.0f;
        const float Gx = (gx - cx) * inv_r + cx;
        const float ix = (Gx + 1.0f) * 0.5f * 511.0f;
        const float x0 = floorf(ix);
        const float tx = ix - x0;
        const int x0i = (int)x0;
        wxB0 = k2f(tx + 1.0f); wxB1 = k1f(tx);
        wxB2 = k1f(1.0f - tx); wxB3 = k2f(2.0f - tx);
        sB0 = swz(reflect_clip(x0i - 1, W)); sB1 = swz(reflect_clip(x0i,     W));
        sB2 = swz(reflect_clip(x0i + 1, W)); sB3 = swz(reflect_clip(x0i + 2, W));
    }

    __shared__ float tmp[C][W];   // 16 KiB, swizzled rows (sole LDS object)

    // ---- vertical combine -> swizzled LDS ----
    {
        const int v    = (cc4 >> 5) & 31;
        const int base = cc4 ^ (v & ~3);
        const int p    = v & 3;
        const bool q1 = (p & 1) != 0;
        const bool q2 = (p & 2) != 0;
#define COMB1(cc, a0, a1, a2, a3)                                          \
        {                                                                  \
            float e0 = wy0 * a0.x + wy1 * a1.x + wy2 * a2.x + wy3 * a3.x;  \
            float e1 = wy0 * a0.y + wy1 * a1.y + wy2 * a2.y + wy3 * a3.y;  \
            float e2 = wy0 * a0.z + wy1 * a1.z + wy2 * a2.z + wy3 * a3.z;  \
            float e3 = wy0 * a0.w + wy1 * a1.w + wy2 * a2.w + wy3 * a3.w;  \
            float t0 = q1 ? e1 : e0;                                       \
            float t1 = q1 ? e0 : e1;                                       \
            float t2 = q1 ? e3 : e2;                                       \
            float t3 = q1 ? e2 : e3;                                       \
            float u0 = q2 ? t2 : t0;                                       \
            float u1 = q2 ? t3 : t1;                                       \
            float u2 = q2 ? t0 : t2;                                       \
            float u3 = q2 ? t1 : t3;                                       \
            *(float4*)&tmp[cc][base] = make_float4(u0, u1, u2, u3);        \
        }
        COMB1(ch0 + 0, p00, p01, p02, p03);
        COMB1(ch0 + 2, p10, p11, p12, p13);
        COMB1(ch0 + 4, p20, p21, p22, p23);
        COMB1(ch0 + 6, p30, p31, p32, p33);
#undef COMB1
    }
    __syncthreads();

    // ---- phase 2: paired-channel LDS reads (c, c+4 in one inst), 2-deep
    // pipeline with counted lgkmcnt. Raw LDS byte offsets: tmp is the only
    // __shared__ object -> addr(c,s) = base + c*2048 + s*4. ----
    const unsigned ldsbase = (unsigned)(uintptr_t)&tmp[0][0];
    const unsigned oA0 = (unsigned)(sA0 << 2), oA1 = (unsigned)(sA1 << 2);
    const unsigned oA2 = (unsigned)(sA2 << 2), oA3 = (unsigned)(sA3 << 2);
    const unsigned oB0 = (unsigned)(sB0 << 2), oB1 = (unsigned)(sB1 << 2);
    const unsigned oB2 = (unsigned)(sB2 << 2), oB3 = (unsigned)(sB3 << 2);
    float* obase = out + ((size_t)b * C * H + h) * W + 2 * t;

#define DECL_ISSUE(cc)                                                     \
    f32x2 qa0_##cc, qa1_##cc, qa2_##cc, qa3_##cc;                          \
    f32x2 qb0_##cc, qb1_##cc, qb2_##cc, qb3_##cc;                          \
    {                                                                      \
        const unsigned ab = ldsbase + ((unsigned)(cc) << 11);              \
        DSR2(qa0_##cc, ab + oA0);                                          \
        DSR2(qa1_##cc, ab + oA1);                                          \
        DSR2(qa2_##cc, ab + oA2);                                          \
        DSR2(qa3_##cc, ab + oA3);                                          \
        DSR2(qb0_##cc, ab + oB0);                                          \
        DSR2(qb1_##cc, ab + oB1);                                          \
        DSR2(qb2_##cc, ab + oB2);                                          \
        DSR2(qb3_##cc, ab + oB3);                                          \
    }

#define COMPUTE_STORE(cc)                                                  \
    {                                                                      \
        const float lo0 = wxA0 * qa0_##cc.x + wxA1 * qa1_##cc.x            \
                        + wxA2 * qa2_##cc.x + wxA3 * qa3_##cc.x;           \
        const float lo1 = wxB0 * qb0_##cc.x + wxB1 * qb1_##cc.x            \
                        + wxB2 * qb2_##cc.x + wxB3 * qb3_##cc.x;           \
        const float hi0 = wxA0 * qa0_##cc.y + wxA1 * qa1_##cc.y            \
                        + wxA2 * qa2_##cc.y + wxA3 * qa3_##cc.y;           \
        const float hi1 = wxB0 * qb0_##cc.y + wxB1 * qb1_##cc.y            \
                        + wxB2 * qb2_##cc.y + wxB3 * qb3_##cc.y;           \
        float2 vlo = make_float2(lo0, lo1);                                \
        float2 vhi = make_float2(hi0, hi1);                                \
        double dlo, dhi;                                                   \
        memcpy(&dlo, &vlo, 8);                                             \
        memcpy(&dhi, &vhi, 8);                                             \
        __builtin_nontemporal_store(dlo, (double*)(obase + (size_t)(cc) * HW));       \
        __builtin_nontemporal_store(dhi, (double*)(obase + (size_t)((cc) + 4) * HW)); \
    }

    DECL_ISSUE(0);
    DECL_ISSUE(1);
    asm volatile("s_waitcnt lgkmcnt(8)" ::: "memory");
    __builtin_amdgcn_sched_barrier(0);
    COMPUTE_STORE(0);
    DECL_ISSUE(2);
    asm volatile("s_waitcnt lgkmcnt(8)" ::: "memory");
    __builtin_amdgcn_sched_barrier(0);
    COMPUTE_STORE(1);
    DECL_ISSUE(3);
    asm volatile("s_waitcnt lgkmcnt(8)" ::: "memory");
    __builtin_amdgcn_sched_barrier(0);
    COMPUTE_STORE(2);
    asm volatile("s_waitcnt lgkmcnt(0)" ::: "memory");
    __builtin_amdgcn_sched_barrier(0);
    COMPUTE_STORE(3);
#undef DECL_ISSUE
#undef COMPUTE_STORE
}

extern "C" void kernel_launch(void* const* d_in, const int* in_sizes, int n_in,
                              void* d_out, int out_size, void* d_ws, size_t ws_size,
                              hipStream_t stream) {
    const float* x      = (const float*)d_in[0];
    const float* rate   = (const float*)d_in[1];
    const float* center = (const float*)d_in[2];
    float* out          = (float*)d_out;

    constexpr int B = 16, H = 512;
    dim3 grid(B * H);
    dim3 block(256);
    pds12_kernel<<<grid, block, 0, stream>>>(x, rate, center, out);
}